// Round 1
// 854.790 us; speedup vs baseline: 2.9815x; 2.9815x over previous
//
#include <hip/hip_runtime.h>
#include <hip/hip_bf16.h>

typedef __hip_bfloat16 bf16;
typedef __attribute__((ext_vector_type(8))) short short8_t;
typedef __attribute__((ext_vector_type(4))) float f32x4;

#define B_ROWS 32768

__device__ __forceinline__ float to_f(float x) { return x; }
__device__ __forceinline__ float to_f(bf16 x) { return __bfloat162float(x); }

// float -> bf16 bits, round-to-nearest-even
__device__ __forceinline__ unsigned short f2bf(float f) {
    union { float f; unsigned int u; } c; c.f = f;
    unsigned int u = c.u;
    unsigned int rb = ((u >> 16) & 1u) + 0x7fffu;
    return (unsigned short)((u + rb) >> 16);
}

// stage 8 elements (16B of bf16) into LDS
__device__ __forceinline__ void stage8(const bf16* __restrict__ src, bf16* dst) {
    *(uint4*)dst = *(const uint4*)src;
}
__device__ __forceinline__ void stage8(const float* __restrict__ src, bf16* dst) {
    const float4 a = *(const float4*)src;
    const float4 b = *(const float4*)(src + 4);
    union { uint4 u; unsigned short h[8]; } r;
    r.h[0] = f2bf(a.x); r.h[1] = f2bf(a.y); r.h[2] = f2bf(a.z); r.h[3] = f2bf(a.w);
    r.h[4] = f2bf(b.x); r.h[5] = f2bf(b.y); r.h[6] = f2bf(b.z); r.h[7] = f2bf(b.w);
    *(uint4*)dst = r.u;
}

// ---------------------------------------------------------------------------
// MFMA GEMM: out[M,N] = act(A[M,K] @ W[K,N] + bias)
// A: fp32 or bf16, row-major (lda). Wt: prepacked bf16 W^T [Nr>=ceil128(N)][kpad],
// zero-filled pads. K % 64 == 0 (padded), M % 128 == 0.
// Tile 128x128, BK=64, 256 threads = 4 waves (2x2 of 64x64), 4x4 16x16x32 frags.
// Swapped operands: mfma(Wfrag, Afrag) -> acc reg dim = 4 consecutive n.
// nstore >= N: columns [N, nstore) are written as zeros (bf16 out) for padding.
// ---------------------------------------------------------------------------
template <typename TA, int ACT>  // ACT: 0 none, 1 relu, 2 sigmoid
__global__ __launch_bounds__(256) void gemm_mfma(
    const TA* __restrict__ A, int lda,
    const bf16* __restrict__ Wt, int kpad,
    const float* __restrict__ bias,
    float* __restrict__ outf, int ldof,
    bf16* __restrict__ outb, int ldob,
    int M, int N, int nstore, int K)
{
    __shared__ __align__(16) bf16 As[128 * 64];
    __shared__ __align__(16) bf16 Bs[128 * 64];

    const int tid = threadIdx.x;
    const int lane = tid & 63;
    const int w = tid >> 6;
    const int wr = w >> 1, wc = w & 1;          // wave tile (64x64) coords
    const int m0 = blockIdx.y * 128, n0 = blockIdx.x * 128;
    const int kq = lane >> 4, lr = lane & 15;

    f32x4 acc[4][4] = {};                        // [mi][ni]

    // staging: thread covers (row = srow + p*32, 8-elem chunk sch), p = 0..3
    const int srow = tid >> 3;                   // 0..31
    const int sch = tid & 7;                     // 0..7
    const int sx = sch ^ (srow & 7);             // swizzled chunk for writes

    for (int k0 = 0; k0 < K; k0 += 64) {
#pragma unroll
        for (int p = 0; p < 4; ++p) {
            const int row = srow + p * 32;
            const int dst = row * 64 + (sx << 3);
            stage8(A + (size_t)(m0 + row) * lda + (k0 + sch * 8), &As[dst]);
            stage8(Wt + (size_t)(n0 + row) * kpad + (k0 + sch * 8), &Bs[dst]);
        }
        __syncthreads();
#pragma unroll
        for (int kk = 0; kk < 2; ++kk) {
            const int co = ((kk * 4 + kq) ^ (lr & 7)) << 3;
            short8_t am[4], wf[4];
#pragma unroll
            for (int i = 0; i < 4; ++i) {
                am[i] = *(const short8_t*)&As[(wr * 64 + i * 16 + lr) * 64 + co];
                wf[i] = *(const short8_t*)&Bs[(wc * 64 + i * 16 + lr) * 64 + co];
            }
#pragma unroll
            for (int i = 0; i < 4; ++i)
#pragma unroll
                for (int j = 0; j < 4; ++j)
                    acc[i][j] = __builtin_amdgcn_mfma_f32_16x16x32_bf16(
                        wf[j], am[i], acc[i][j], 0, 0, 0);
        }
        __syncthreads();
    }

    // epilogue: lane holds m = ...+lr, regs hold 4 consecutive n
#pragma unroll
    for (int mi = 0; mi < 4; ++mi) {
        const size_t m = m0 + wr * 64 + mi * 16 + lr;
#pragma unroll
        for (int ni = 0; ni < 4; ++ni) {
            const int nb = n0 + wc * 64 + ni * 16 + 4 * kq;
            if (nb >= nstore) continue;
            float vv[4];
#pragma unroll
            for (int r = 0; r < 4; ++r) {
                const int n = nb + r;
                float v = acc[mi][ni][r] + ((n < N) ? bias[n] : 0.f);
                if (ACT == 1) v = fmaxf(v, 0.f);
                if (ACT == 2) v = (n < N) ? 1.f / (1.f + __expf(-v)) : 0.f;
                vv[r] = v;
            }
            if (outf) {
                if (nb + 3 < N) {
                    float4 f4; f4.x = vv[0]; f4.y = vv[1]; f4.z = vv[2]; f4.w = vv[3];
                    *(float4*)&outf[m * ldof + nb] = f4;
                } else {
#pragma unroll
                    for (int r = 0; r < 4; ++r)
                        if (nb + r < N) outf[m * ldof + nb + r] = vv[r];
                }
            }
            if (outb) {
                if (nb + 3 < nstore) {
                    union { uint2 u; unsigned short h[4]; } pk;
                    pk.h[0] = f2bf(vv[0]); pk.h[1] = f2bf(vv[1]);
                    pk.h[2] = f2bf(vv[2]); pk.h[3] = f2bf(vv[3]);
                    *(uint2*)&outb[m * ldob + nb] = pk.u;
                } else {
#pragma unroll
                    for (int r = 0; r < 4; ++r)
                        if (nb + r < nstore)
                            ((unsigned short*)outb)[m * ldob + nb + r] = f2bf(vv[r]);
                }
            }
        }
    }
}

// ---------------------------------------------------------------------------
// Weight prepack: fp32 W[K,N] -> bf16 W^T [Nr][Kpad], zero pads. 12 weights.
// ---------------------------------------------------------------------------
struct PrepackArgs {
    const float* src[12];
    unsigned long long off[12];
    int K[12], N[12], Kpad[12], Nr[12];
};

__global__ __launch_bounds__(256) void prepack_kernel(PrepackArgs a, bf16* wsbase)
{
    const int wI = blockIdx.y;
    const float* __restrict__ src = a.src[wI];
    bf16* dst = wsbase + a.off[wI];
    const int K = a.K[wI], N = a.N[wI], Kpad = a.Kpad[wI];
    const int total = a.Nr[wI] * Kpad;
    for (int e = blockIdx.x * 256 + threadIdx.x; e < total; e += gridDim.x * 256) {
        const int n = e / Kpad, k = e - n * Kpad;
        const float v = (n < N && k < K) ? src[(size_t)k * N + n] : 0.f;
        ((unsigned short*)dst)[e] = f2bf(v);
    }
}

// ---------------------------------------------------------------------------
// Attention over seq-len 2, 4 heads x 64 dims. One wave per (sample, head);
// block 256 = 1 sample. qkv: [NB, 2, 768] bf16. ctxm: [NB,256] bf16 = mean ctx.
// ---------------------------------------------------------------------------
__global__ __launch_bounds__(256) void attn_kernel(
    const bf16* __restrict__ qkv, bf16* __restrict__ ctxm)
{
    const int b = blockIdx.x;
    const int lane = threadIdx.x & 63;
    const bf16* base = qkv + (size_t)b * 1536;
    const int o = (threadIdx.x >> 6) * 64 + lane;

    float q0 = to_f(base[o]),       k0 = to_f(base[256 + o]),       v0 = to_f(base[512 + o]);
    float q1 = to_f(base[768 + o]), k1 = to_f(base[768 + 256 + o]), v1 = to_f(base[768 + 512 + o]);

    float s00 = q0 * k0, s01 = q0 * k1, s10 = q1 * k0, s11 = q1 * k1;
#pragma unroll
    for (int off = 32; off; off >>= 1) {
        s00 += __shfl_xor(s00, off);
        s01 += __shfl_xor(s01, off);
        s10 += __shfl_xor(s10, off);
        s11 += __shfl_xor(s11, off);
    }
    const float sc = 0.125f;  // 1/sqrt(64)
    s00 *= sc; s01 *= sc; s10 *= sc; s11 *= sc;

    float m0 = fmaxf(s00, s01);
    float e00 = __expf(s00 - m0), e01 = __expf(s01 - m0);
    float r0 = 1.f / (e00 + e01);
    float m1 = fmaxf(s10, s11);
    float e10 = __expf(s10 - m1), e11 = __expf(s11 - m1);
    float r1 = 1.f / (e10 + e11);

    float c0 = e00 * r0 * v0 + e01 * r0 * v1;
    float c1 = e10 * r1 * v0 + e11 * r1 * v1;
    ctxm[(size_t)b * 256 + o] = __float2bfloat16(0.5f * (c0 + c1));
}

// ---------------------------------------------------------------------------
// Row softmax over 372 genus logits (bf16 in -> fp32 out + bf16 [B,384] padded)
// ---------------------------------------------------------------------------
__global__ __launch_bounds__(64) void softmax372_kernel(
    const bf16* __restrict__ in, float* __restrict__ outf, bf16* __restrict__ outb)
{
    const int b = blockIdx.x;
    const int lane = threadIdx.x;
    const bf16* row = in + (size_t)b * 372;

    float v[6];
    float mx = -1e30f;
#pragma unroll
    for (int i = 0; i < 6; ++i) {
        int idx = lane + i * 64;
        v[i] = (idx < 372) ? to_f(row[idx]) : -1e30f;
        mx = fmaxf(mx, v[i]);
    }
#pragma unroll
    for (int off = 32; off; off >>= 1) mx = fmaxf(mx, __shfl_xor(mx, off));

    float s = 0.f;
#pragma unroll
    for (int i = 0; i < 6; ++i) {
        int idx = lane + i * 64;
        if (idx < 372) { v[i] = __expf(v[i] - mx); s += v[i]; }
    }
#pragma unroll
    for (int off = 32; off; off >>= 1) s += __shfl_xor(s, off);
    float r = 1.f / s;

#pragma unroll
    for (int i = 0; i < 6; ++i) {
        int idx = lane + i * 64;
        if (idx < 372) {
            float p = v[i] * r;
            outf[(size_t)b * 372 + idx] = p;
            outb[(size_t)b * 384 + idx] = __float2bfloat16(p);
        } else if (idx < 384) {
            outb[(size_t)b * 384 + idx] = __float2bfloat16(0.f);
        }
    }
}

// ---------------------------------------------------------------------------
// species[b,s] = genus[b, sg[s]] * local[b, sl[s]]  (fp32 in/out)
// ---------------------------------------------------------------------------
__global__ __launch_bounds__(256) void species_kernel(
    const float* __restrict__ g, const float* __restrict__ ll,
    const int* __restrict__ sg, const int* __restrict__ sl,
    float* __restrict__ out)
{
    const int s = blockIdx.x * 256 + threadIdx.x;
    const int b = blockIdx.y;
    if (s < 1050) {
        out[(size_t)b * 1050 + s] =
            g[(size_t)b * 372 + sg[s]] * ll[(size_t)b * 23 + sl[s]];
    }
}

extern "C" void kernel_launch(void* const* d_in, const int* in_sizes, int n_in,
                              void* d_out, int out_size, void* d_ws, size_t ws_size,
                              hipStream_t stream)
{
    const int B = B_ROWS;
    const float* dna   = (const float*)d_in[0];
    const float* img   = (const float*)d_in[1];
    const float* W_dna = (const float*)d_in[2];  const float* b_dna = (const float*)d_in[3];
    const float* W_img = (const float*)d_in[4];  const float* b_img = (const float*)d_in[5];
    const float* W_qkv = (const float*)d_in[6];  const float* b_qkv = (const float*)d_in[7];
    const float* W_o   = (const float*)d_in[8];  const float* b_o   = (const float*)d_in[9];
    const float* W_f1  = (const float*)d_in[10]; const float* b_f1  = (const float*)d_in[11];
    const float* W_f2  = (const float*)d_in[12]; const float* b_f2  = (const float*)d_in[13];
    const float* W_d1  = (const float*)d_in[14]; const float* b_d1  = (const float*)d_in[15];
    const float* W_d2  = (const float*)d_in[16]; const float* b_d2  = (const float*)d_in[17];
    const float* W_fp  = (const float*)d_in[18]; const float* b_fp  = (const float*)d_in[19];
    const float* W_ge  = (const float*)d_in[20]; const float* b_ge  = (const float*)d_in[21];
    const float* W_s1  = (const float*)d_in[22]; const float* b_s1  = (const float*)d_in[23];
    const float* W_s2  = (const float*)d_in[24]; const float* b_s2  = (const float*)d_in[25];
    const int*   sg    = (const int*)d_in[26];
    const int*   sl    = (const int*)d_in[27];

    bf16* ws = (bf16*)d_ws;

    // ---- weight prepack (bf16 W^T, padded) ----
    // order: dna, img, qkv, o, f1, f2, d1, d2, fp, ge, s1, s2
    static const int KK[12] = {768, 512, 256, 256, 256, 256, 256, 744, 256, 372, 192, 64};
    static const int NN[12] = {256, 256, 768, 256, 256, 256, 744, 372, 128,  64,  64, 23};
    const float* SRC[12] = {W_dna, W_img, W_qkv, W_o, W_f1, W_f2, W_d1, W_d2, W_fp, W_ge, W_s1, W_s2};
    PrepackArgs pa;
    size_t woff[12];
    size_t off = 0;
    for (int i = 0; i < 12; ++i) {
        pa.src[i] = SRC[i]; pa.K[i] = KK[i]; pa.N[i] = NN[i];
        pa.Kpad[i] = (KK[i] + 63) & ~63;
        pa.Nr[i]   = (NN[i] + 127) & ~127;
        pa.off[i] = off; woff[i] = off;
        off += (size_t)pa.Kpad[i] * pa.Nr[i];
    }
    const size_t AOFF = off;  // 1,327,104 elems; activations peak AOFF + B*1396 (~94 MB)

    bf16* seq  = ws + AOFF;                         // [B,2,256]
    bf16* qkvc = ws + AOFF + (size_t)B * 512;       // [B/2 rows, 768] per chunk
    bf16* ctxm = ws + AOFF + (size_t)B * 896;       // [B,256]
    bf16* t1   = ws + AOFF;                         // [B,256]  (seq dead)
    bf16* t2   = ws + AOFF + (size_t)B * 256;       // [B,256]
    bf16* fbuf = ws + AOFF;                         // [B,256]  (t1 dead)
    bf16* h1   = ws + AOFF + (size_t)B * 256;       // [B,768]  (t2/ctxm dead)
    bf16* g    = ws + AOFF + (size_t)B * 1024;      // [B,372]
    bf16* gbf  = ws + AOFF + (size_t)B * 256;       // [B,384]  (h1 dead)
    bf16* gf   = ws + AOFF + (size_t)B * 640;       // [B,192]
    bf16* sh   = ws + AOFF + (size_t)B * 832;       // [B,64]

    float* out       = (float*)d_out;
    float* o_species = out;                          // [B,1050]
    float* o_local   = out + (size_t)B * 1050;       // [B,23]
    float* o_genus   = out + (size_t)B * 1073;       // [B,372]
    float* o_fused   = out + (size_t)B * 1445;       // [B,256]
    float* o_red     = out + (size_t)B * 1701;       // [B,128]

    prepack_kernel<<<dim3(32, 12), 256, 0, stream>>>(pa, ws);

#define NOF (float*)nullptr, 0
#define NOB (bf16*)nullptr, 0

    // dna_proj / img_proj -> seq [B,2,256]
    gemm_mfma<float, 0><<<dim3(2, 256), 256, 0, stream>>>(
        dna, 768, ws + woff[0], 768, b_dna, NOF, seq, 512, B, 256, 256, 768);
    gemm_mfma<float, 0><<<dim3(2, 256), 256, 0, stream>>>(
        img, 512, ws + woff[1], 512, b_img, NOF, seq + 256, 512, B, 256, 256, 512);
    // qkv + attention, 4 chunks of B/4 samples (B/2 rows of the [2B,768] GEMM)
    for (int c = 0; c < 4; ++c) {
        gemm_mfma<bf16, 0><<<dim3(6, 128), 256, 0, stream>>>(
            seq + (size_t)c * (B / 2) * 256, 256, ws + woff[2], 256, b_qkv,
            NOF, qkvc, 768, B / 2, 768, 768, 256);
        attn_kernel<<<B / 4, 256, 0, stream>>>(qkvc, ctxm + (size_t)c * (B / 4) * 256);
    }
    // t1 = ctxm @ W_o + b_o (mean folded before W_o)
    gemm_mfma<bf16, 0><<<dim3(2, 256), 256, 0, stream>>>(
        ctxm, 256, ws + woff[3], 256, b_o, NOF, t1, 256, B, 256, 256, 256);
    // t2 = relu(t1 @ W_f1 + b_f1)
    gemm_mfma<bf16, 1><<<dim3(2, 256), 256, 0, stream>>>(
        t1, 256, ws + woff[4], 256, b_f1, NOF, t2, 256, B, 256, 256, 256);
    // fused = t2 @ W_f2 + b_f2 -> output #4 (fp32) + bf16 copy
    gemm_mfma<bf16, 0><<<dim3(2, 256), 256, 0, stream>>>(
        t2, 256, ws + woff[5], 256, b_f2, o_fused, 256, fbuf, 256, B, 256, 256, 256);
    // h1 = sigmoid(fused @ W_d1 + b_d1) [B,744] stored padded to 768 (zeros)
    gemm_mfma<bf16, 2><<<dim3(6, 256), 256, 0, stream>>>(
        fbuf, 256, ws + woff[6], 256, b_d1, NOF, h1, 768, B, 744, 768, 256);
    // genus logits (pre-softmax) [B,372], K padded to 768 (h1 zeros x Wt zeros)
    gemm_mfma<bf16, 0><<<dim3(3, 256), 256, 0, stream>>>(
        h1, 768, ws + woff[7], 768, b_d2, NOF, g, 372, B, 372, 372, 768);
    // genus softmax -> output #3 (fp32) + bf16 padded copy [B,384]
    softmax372_kernel<<<B, 64, 0, stream>>>(g, o_genus, gbf);
    // genus_emb = genus @ W_ge + b_ge -> gf[:,0:64]
    gemm_mfma<bf16, 0><<<dim3(1, 256), 256, 0, stream>>>(
        gbf, 384, ws + woff[9], 384, b_ge, NOF, gf, 192, B, 64, 64, 384);
    // reduced_fused = fused @ W_fp + b_fp -> output #5 (fp32) and gf[:,64:192]
    gemm_mfma<bf16, 0><<<dim3(1, 256), 256, 0, stream>>>(
        fbuf, 256, ws + woff[8], 256, b_fp, o_red, 128, gf + 64, 192, B, 128, 128, 256);
    // sh = sigmoid(gf @ W_s1 + b_s1) [B,64]
    gemm_mfma<bf16, 2><<<dim3(1, 256), 256, 0, stream>>>(
        gf, 192, ws + woff[10], 192, b_s1, NOF, sh, 64, B, 64, 64, 192);
    // local_logits = sh @ W_s2 + b_s2 [B,23] -> output #2 (fp32)
    gemm_mfma<bf16, 0><<<dim3(1, 256), 256, 0, stream>>>(
        sh, 64, ws + woff[11], 64, b_s2, o_local, 23, NOB, B, 23, 23, 64);
    // species -> output #1 (fp32)
    species_kernel<<<dim3(5, B), 256, 0, stream>>>(o_genus, o_local, sg, sl, o_species);
#undef NOF
#undef NOB
}

// Round 3
// 804.132 us; speedup vs baseline: 3.1694x; 1.0630x over previous
//
#include <hip/hip_runtime.h>
#include <hip/hip_bf16.h>

typedef __hip_bfloat16 bf16;
typedef __attribute__((ext_vector_type(8))) short short8_t;
typedef __attribute__((ext_vector_type(4))) float f32x4;

#define B_ROWS 32768

__device__ __forceinline__ float to_f(float x) { return x; }
__device__ __forceinline__ float to_f(bf16 x) { return __bfloat162float(x); }

// float -> bf16 bits, round-to-nearest-even
__device__ __forceinline__ unsigned short f2bf(float f) {
    union { float f; unsigned int u; } c; c.f = f;
    unsigned int u = c.u;
    unsigned int rb = ((u >> 16) & 1u) + 0x7fffu;
    return (unsigned short)((u + rb) >> 16);
}

// async global->LDS, 16 bytes per lane. LDS dest must be wave-uniform base +
// lane*16 (m104 contract): callers pass contiguous per-lane dests within a wave.
__device__ __forceinline__ void glds16(const void* g, void* s) {
    __builtin_amdgcn_global_load_lds(
        (const __attribute__((address_space(1))) unsigned int*)g,
        (__attribute__((address_space(3))) unsigned int*)s, 16, 0, 0);
}

// reg-stage 8 fp32 -> 8 bf16 (16B) into LDS
__device__ __forceinline__ void stage8f(const float* __restrict__ src, bf16* dst) {
    const float4 a = *(const float4*)src;
    const float4 b = *(const float4*)(src + 4);
    union { uint4 u; unsigned short h[8]; } r;
    r.h[0] = f2bf(a.x); r.h[1] = f2bf(a.y); r.h[2] = f2bf(a.z); r.h[3] = f2bf(a.w);
    r.h[4] = f2bf(b.x); r.h[5] = f2bf(b.y); r.h[6] = f2bf(b.z); r.h[7] = f2bf(b.w);
    *(uint4*)dst = r.u;
}

// ---------------------------------------------------------------------------
// MFMA GEMM: out[M,N] = act(A[M,K] @ W[K,N] + bias)
// A: fp32 (reg-staged convert) or bf16 (global_load_lds), row-major (lda;
// bf16 lda must be a multiple of 8). Wt: prepacked bf16 W^T [Nr>=tilepad(N)][kpad],
// zero pads. K % 64 == 0, M % 128 == 0. Launch grids guarantee n0+BN <= Nr.
// Tile 128xBN (BN in {128,256}), BK=64, BN*2 threads (4 or 8 waves of 64x64).
// LDS layout: [row][chunk ^ (row&7)] of 8-elem chunks; glds keeps LDS linear
// and swizzles the *source* chunk instead (same involution both sides, rule #21).
// Swapped operands: mfma(Wfrag, Afrag) -> acc reg dim = 4 consecutive n.
// nstore >= N: bf16 out columns [N, nstore) are written as zeros.
// ---------------------------------------------------------------------------
template <typename TA, int BN, int ACT>  // ACT: 0 none, 1 relu, 2 sigmoid
__global__ __launch_bounds__(BN * 2) void gemm_mfma(
    const TA* __restrict__ A, int lda,
    const bf16* __restrict__ Wt, int kpad,
    const float* __restrict__ bias,
    float* __restrict__ outf, int ldof,
    bf16* __restrict__ outb, int ldob,
    int M, int N, int nstore, int K)
{
    constexpr int NT = BN * 2;
    constexpr int WC = BN / 64;
    __shared__ __align__(16) bf16 As[128 * 64];
    __shared__ __align__(16) bf16 Bs[BN * 64];

    const int tid = threadIdx.x;
    const int lane = tid & 63;
    const int w = tid >> 6;
    const int wr = w / WC, wc = w % WC;
    const int m0 = blockIdx.y * 128, n0 = blockIdx.x * BN;
    const int kq = lane >> 4, lr = lane & 15;

    f32x4 acc[4][4] = {};

    for (int k0 = 0; k0 < K; k0 += 64) {
        if constexpr (sizeof(TA) == 2) {
#pragma unroll
            for (int j = 0; j < 1024 / NT; ++j) {
                const int c = tid + j * NT;
                const int row = c >> 3, sx = (c & 7) ^ (row & 7);
                glds16(A + (size_t)(m0 + row) * lda + k0 + sx * 8, &As[c * 8]);
            }
        } else {
#pragma unroll
            for (int j = 0; j < 1024 / NT; ++j) {
                const int c = tid + j * NT;
                const int row = c >> 3, sx = (c & 7) ^ (row & 7);
                stage8f(A + (size_t)(m0 + row) * lda + k0 + (c & 7) * 8,
                        &As[row * 64 + sx * 8]);
            }
        }
#pragma unroll
        for (int j = 0; j < BN * 8 / NT; ++j) {
            const int c = tid + j * NT;
            const int row = c >> 3, sx = (c & 7) ^ (row & 7);
            glds16(Wt + (size_t)(n0 + row) * kpad + k0 + sx * 8, &Bs[c * 8]);
        }
        __syncthreads();
#pragma unroll
        for (int kk = 0; kk < 2; ++kk) {
            const int co = ((kk * 4 + kq) ^ (lr & 7)) << 3;
            short8_t am[4], wf[4];
#pragma unroll
            for (int i = 0; i < 4; ++i) {
                am[i] = *(const short8_t*)&As[(wr * 64 + i * 16 + lr) * 64 + co];
                wf[i] = *(const short8_t*)&Bs[(wc * 64 + i * 16 + lr) * 64 + co];
            }
#pragma unroll
            for (int i = 0; i < 4; ++i)
#pragma unroll
                for (int j = 0; j < 4; ++j)
                    acc[i][j] = __builtin_amdgcn_mfma_f32_16x16x32_bf16(
                        wf[j], am[i], acc[i][j], 0, 0, 0);
        }
        __syncthreads();
    }

#pragma unroll
    for (int mi = 0; mi < 4; ++mi) {
        const size_t m = m0 + wr * 64 + mi * 16 + lr;
#pragma unroll
        for (int ni = 0; ni < 4; ++ni) {
            const int nb = n0 + wc * 64 + ni * 16 + 4 * kq;
            if (nb >= nstore) continue;
            float vv[4];
#pragma unroll
            for (int r = 0; r < 4; ++r) {
                const int n = nb + r;
                float v = acc[mi][ni][r] + ((n < N) ? bias[n] : 0.f);
                if (ACT == 1) v = fmaxf(v, 0.f);
                if (ACT == 2) v = (n < N) ? 1.f / (1.f + __expf(-v)) : 0.f;
                vv[r] = v;
            }
            if (outf) {
                if (nb + 3 < N) {
                    float4 f4; f4.x = vv[0]; f4.y = vv[1]; f4.z = vv[2]; f4.w = vv[3];
                    *(float4*)&outf[m * ldof + nb] = f4;
                } else {
#pragma unroll
                    for (int r = 0; r < 4; ++r)
                        if (nb + r < N) outf[m * ldof + nb + r] = vv[r];
                }
            }
            if (outb) {
                if (nb + 3 < nstore) {
                    union { uint2 u; unsigned short h[4]; } pk;
                    pk.h[0] = f2bf(vv[0]); pk.h[1] = f2bf(vv[1]);
                    pk.h[2] = f2bf(vv[2]); pk.h[3] = f2bf(vv[3]);
                    *(uint2*)&outb[m * ldob + nb] = pk.u;
                } else {
#pragma unroll
                    for (int r = 0; r < 4; ++r)
                        if (nb + r < nstore)
                            ((unsigned short*)outb)[m * ldob + nb + r] = f2bf(vv[r]);
                }
            }
        }
    }
}

// ---------------------------------------------------------------------------
// Fused MLP chain: fused = (relu((ctxm@Wo+bo)@Wf1+bf1))@Wf2+bf2
// One block = 128 rows x full 256 cols, 512 threads (8 waves 2x4).
// Intermediates live in LDS T[4][128*64] in the GEMM fragment layout
// (cell (m,n) at T[n>>6][m*64 + ((((n&63)>>3)^(m&7))<<3) + (n&7)], matching
// the compute-side read swizzle since m&7 == lr&7).
// LDS total = 16 + 32 + 64 = 112 KB (< the 128 KB proven by the 8-phase example).
// ---------------------------------------------------------------------------
#define MLP3_STAGE_W(WP)                                                       \
    _Pragma("unroll")                                                          \
    for (int j = 0; j < 4; ++j) {                                              \
        const int c = tid + j * 512;                                           \
        const int row = c >> 3, sx = (c & 7) ^ (row & 7);                      \
        glds16(WP + (size_t)row * 256 + ks * 64 + sx * 8, &Wb[c * 8]);         \
    }

#define MLP3_COMPUTE(ASRC)                                                     \
    _Pragma("unroll")                                                          \
    for (int kk = 0; kk < 2; ++kk) {                                           \
        const int co = ((kk * 4 + kq) ^ (lr & 7)) << 3;                        \
        short8_t am[4], wf[4];                                                 \
        _Pragma("unroll")                                                      \
        for (int i = 0; i < 4; ++i) {                                          \
            am[i] = *(const short8_t*)&(ASRC)[(wr * 64 + i * 16 + lr) * 64 + co]; \
            wf[i] = *(const short8_t*)&Wb[(wc * 64 + i * 16 + lr) * 64 + co];  \
        }                                                                      \
        _Pragma("unroll")                                                      \
        for (int i = 0; i < 4; ++i)                                            \
            _Pragma("unroll")                                                  \
            for (int j2 = 0; j2 < 4; ++j2)                                     \
                acc[i][j2] = __builtin_amdgcn_mfma_f32_16x16x32_bf16(          \
                    wf[j2], am[i], acc[i][j2], 0, 0, 0);                       \
    }

#define MLP3_STORE_T(BIASP, RELU)                                              \
    _Pragma("unroll")                                                          \
    for (int mi = 0; mi < 4; ++mi) {                                           \
        const int m = wr * 64 + mi * 16 + lr;                                  \
        _Pragma("unroll")                                                      \
        for (int ni = 0; ni < 4; ++ni) {                                       \
            const int nb = wc * 64 + ni * 16 + 4 * kq;                         \
            union { unsigned long long u; unsigned short h[4]; } pk;           \
            _Pragma("unroll")                                                  \
            for (int r = 0; r < 4; ++r) {                                      \
                float v = acc[mi][ni][r] + BIASP[nb + r];                      \
                if (RELU) v = fmaxf(v, 0.f);                                   \
                pk.h[r] = f2bf(v);                                             \
            }                                                                  \
            *(unsigned long long*)&T[nb >> 6]                                  \
                [m * 64 + ((((nb & 63) >> 3) ^ (m & 7)) << 3) + (nb & 7)] = pk.u; \
        }                                                                      \
    }

#define ZERO_ACC                                                               \
    _Pragma("unroll")                                                          \
    for (int i = 0; i < 4; ++i)                                                \
        _Pragma("unroll")                                                      \
        for (int j2 = 0; j2 < 4; ++j2) acc[i][j2] = f32x4{0.f, 0.f, 0.f, 0.f};

__global__ __launch_bounds__(512) void mlp3_kernel(
    const bf16* __restrict__ ctxm,
    const bf16* __restrict__ Wo, const float* __restrict__ b_o,
    const bf16* __restrict__ Wf1, const float* __restrict__ b_f1,
    const bf16* __restrict__ Wf2, const float* __restrict__ b_f2,
    float* __restrict__ o_fused, bf16* __restrict__ fbuf)
{
    __shared__ __align__(16) bf16 Ab[128 * 64];
    __shared__ __align__(16) bf16 Wb[256 * 64];
    __shared__ __align__(16) bf16 T[4][128 * 64];

    const int tid = threadIdx.x, lane = tid & 63, w = tid >> 6;
    const int wr = w >> 2, wc = w & 3;
    const int m0 = blockIdx.x * 128;
    const int kq = lane >> 4, lr = lane & 15;

    f32x4 acc[4][4];
    ZERO_ACC

    // GEMM1: t1 = ctxm @ Wo + b_o
    for (int ks = 0; ks < 4; ++ks) {
#pragma unroll
        for (int j = 0; j < 2; ++j) {
            const int c = tid + j * 512;
            const int row = c >> 3, sx = (c & 7) ^ (row & 7);
            glds16(ctxm + (size_t)(m0 + row) * 256 + ks * 64 + sx * 8, &Ab[c * 8]);
        }
        MLP3_STAGE_W(Wo)
        __syncthreads();
        MLP3_COMPUTE(Ab)
        __syncthreads();
    }
    MLP3_STORE_T(b_o, false)
    __syncthreads();

    // GEMM2: t2 = relu(t1 @ Wf1 + b_f1)
    ZERO_ACC
    for (int ks = 0; ks < 4; ++ks) {
        MLP3_STAGE_W(Wf1)
        __syncthreads();
        MLP3_COMPUTE(T[ks])
        __syncthreads();
    }
    MLP3_STORE_T(b_f1, true)
    __syncthreads();

    // GEMM3: fused = t2 @ Wf2 + b_f2
    ZERO_ACC
    for (int ks = 0; ks < 4; ++ks) {
        MLP3_STAGE_W(Wf2)
        __syncthreads();
        MLP3_COMPUTE(T[ks])
        __syncthreads();
    }
#pragma unroll
    for (int mi = 0; mi < 4; ++mi) {
        const size_t m = m0 + wr * 64 + mi * 16 + lr;
#pragma unroll
        for (int ni = 0; ni < 4; ++ni) {
            const int nb = wc * 64 + ni * 16 + 4 * kq;
            float vv[4];
            union { unsigned long long u; unsigned short h[4]; } pk;
#pragma unroll
            for (int r = 0; r < 4; ++r) {
                vv[r] = acc[mi][ni][r] + b_f2[nb + r];
                pk.h[r] = f2bf(vv[r]);
            }
            float4 f4; f4.x = vv[0]; f4.y = vv[1]; f4.z = vv[2]; f4.w = vv[3];
            *(float4*)&o_fused[m * 256 + nb] = f4;
            *(unsigned long long*)&fbuf[m * 256 + nb] = pk.u;
        }
    }
}

// ---------------------------------------------------------------------------
// Weight prepack via LDS 64x64 transpose tiles: fp32 W[K,N] -> bf16 W^T
// [Nr][Kpad], zero pads. Coalesced reads (over n) and writes (over k).
// ---------------------------------------------------------------------------
struct PrepackArgs {
    const float* src[12];
    unsigned long long off[12];
    int K[12], N[12], Kpad[12], Nr[12];
};

__global__ __launch_bounds__(256) void prepack_kernel(PrepackArgs a, bf16* wsbase)
{
    const int wI = blockIdx.y;
    const float* __restrict__ src = a.src[wI];
    bf16* dst = wsbase + a.off[wI];
    const int K = a.K[wI], N = a.N[wI], Kpad = a.Kpad[wI];
    const int tilesK = Kpad >> 6, tilesN = a.Nr[wI] >> 6;
    __shared__ float tile[64][65];

    for (int t = blockIdx.x; t < tilesK * tilesN; t += gridDim.x) {
        const int k0 = (t % tilesK) << 6, n0 = (t / tilesK) << 6;
        const int cc = threadIdx.x & 63, rr = threadIdx.x >> 6;
#pragma unroll
        for (int i = 0; i < 16; ++i) {
            const int k = k0 + rr + i * 4, n = n0 + cc;
            tile[rr + i * 4][cc] = (k < K && n < N) ? src[(size_t)k * N + n] : 0.f;
        }
        __syncthreads();
#pragma unroll
        for (int i = 0; i < 16; ++i) {
            const int nl = rr + i * 4;
            ((unsigned short*)dst)[(size_t)(n0 + nl) * Kpad + k0 + cc] =
                f2bf(tile[cc][nl]);
        }
        __syncthreads();
    }
}

// ---------------------------------------------------------------------------
// Attention over seq-len 2, 4 heads x 64 dims. Block 256 = 1 sample.
// ---------------------------------------------------------------------------
__global__ __launch_bounds__(256) void attn_kernel(
    const bf16* __restrict__ qkv, bf16* __restrict__ ctxm)
{
    const int b = blockIdx.x;
    const int lane = threadIdx.x & 63;
    const bf16* base = qkv + (size_t)b * 1536;
    const int o = (threadIdx.x >> 6) * 64 + lane;

    float q0 = to_f(base[o]),       k0 = to_f(base[256 + o]),       v0 = to_f(base[512 + o]);
    float q1 = to_f(base[768 + o]), k1 = to_f(base[768 + 256 + o]), v1 = to_f(base[768 + 512 + o]);

    float s00 = q0 * k0, s01 = q0 * k1, s10 = q1 * k0, s11 = q1 * k1;
#pragma unroll
    for (int off = 32; off; off >>= 1) {
        s00 += __shfl_xor(s00, off);
        s01 += __shfl_xor(s01, off);
        s10 += __shfl_xor(s10, off);
        s11 += __shfl_xor(s11, off);
    }
    const float sc = 0.125f;
    s00 *= sc; s01 *= sc; s10 *= sc; s11 *= sc;

    float m0 = fmaxf(s00, s01);
    float e00 = __expf(s00 - m0), e01 = __expf(s01 - m0);
    float r0 = 1.f / (e00 + e01);
    float m1 = fmaxf(s10, s11);
    float e10 = __expf(s10 - m1), e11 = __expf(s11 - m1);
    float r1 = 1.f / (e10 + e11);

    float c0 = e00 * r0 * v0 + e01 * r0 * v1;
    float c1 = e10 * r1 * v0 + e11 * r1 * v1;
    ctxm[(size_t)b * 256 + o] = __float2bfloat16(0.5f * (c0 + c1));
}

// ---------------------------------------------------------------------------
// Row softmax over 372 genus logits (bf16 in -> fp32 out + bf16 [B,384] padded)
// ---------------------------------------------------------------------------
__global__ __launch_bounds__(64) void softmax372_kernel(
    const bf16* __restrict__ in, float* __restrict__ outf, bf16* __restrict__ outb)
{
    const int b = blockIdx.x;
    const int lane = threadIdx.x;
    const bf16* row = in + (size_t)b * 372;

    float v[6];
    float mx = -1e30f;
#pragma unroll
    for (int i = 0; i < 6; ++i) {
        int idx = lane + i * 64;
        v[i] = (idx < 372) ? to_f(row[idx]) : -1e30f;
        mx = fmaxf(mx, v[i]);
    }
#pragma unroll
    for (int off = 32; off; off >>= 1) mx = fmaxf(mx, __shfl_xor(mx, off));

    float s = 0.f;
#pragma unroll
    for (int i = 0; i < 6; ++i) {
        int idx = lane + i * 64;
        if (idx < 372) { v[i] = __expf(v[i] - mx); s += v[i]; }
    }
#pragma unroll
    for (int off = 32; off; off >>= 1) s += __shfl_xor(s, off);
    float r = 1.f / s;

#pragma unroll
    for (int i = 0; i < 6; ++i) {
        int idx = lane + i * 64;
        if (idx < 372) {
            float p = v[i] * r;
            outf[(size_t)b * 372 + idx] = p;
            outb[(size_t)b * 384 + idx] = __float2bfloat16(p);
        } else if (idx < 384) {
            outb[(size_t)b * 384 + idx] = __float2bfloat16(0.f);
        }
    }
}

// ---------------------------------------------------------------------------
// species[b,s] = genus[b, sg[s]] * local[b, sl[s]]
// ---------------------------------------------------------------------------
__global__ __launch_bounds__(256) void species_kernel(
    const float* __restrict__ g, const float* __restrict__ ll,
    const int* __restrict__ sg, const int* __restrict__ sl,
    float* __restrict__ out)
{
    const int s = blockIdx.x * 256 + threadIdx.x;
    const int b = blockIdx.y;
    if (s < 1050) {
        out[(size_t)b * 1050 + s] =
            g[(size_t)b * 372 + sg[s]] * ll[(size_t)b * 23 + sl[s]];
    }
}

extern "C" void kernel_launch(void* const* d_in, const int* in_sizes, int n_in,
                              void* d_out, int out_size, void* d_ws, size_t ws_size,
                              hipStream_t stream)
{
    const int B = B_ROWS;
    const float* dna   = (const float*)d_in[0];
    const float* img   = (const float*)d_in[1];
    const float* W_dna = (const float*)d_in[2];  const float* b_dna = (const float*)d_in[3];
    const float* W_img = (const float*)d_in[4];  const float* b_img = (const float*)d_in[5];
    const float* W_qkv = (const float*)d_in[6];  const float* b_qkv = (const float*)d_in[7];
    const float* W_o   = (const float*)d_in[8];  const float* b_o   = (const float*)d_in[9];
    const float* W_f1  = (const float*)d_in[10]; const float* b_f1  = (const float*)d_in[11];
    const float* W_f2  = (const float*)d_in[12]; const float* b_f2  = (const float*)d_in[13];
    const float* W_d1  = (const float*)d_in[14]; const float* b_d1  = (const float*)d_in[15];
    const float* W_d2  = (const float*)d_in[16]; const float* b_d2  = (const float*)d_in[17];
    const float* W_fp  = (const float*)d_in[18]; const float* b_fp  = (const float*)d_in[19];
    const float* W_ge  = (const float*)d_in[20]; const float* b_ge  = (const float*)d_in[21];
    const float* W_s1  = (const float*)d_in[22]; const float* b_s1  = (const float*)d_in[23];
    const float* W_s2  = (const float*)d_in[24]; const float* b_s2  = (const float*)d_in[25];
    const int*   sg    = (const int*)d_in[26];
    const int*   sl    = (const int*)d_in[27];

    bf16* ws = (bf16*)d_ws;

    // ---- weight prepack layout (bf16 W^T, K padded to 64, N padded to 256) ----
    // order: dna, img, qkv, o, f1, f2, d1, d2, fp, ge, s1, s2
    static const int KK[12] = {768, 512, 256, 256, 256, 256, 256, 744, 256, 372, 192, 64};
    static const int NN[12] = {256, 256, 768, 256, 256, 256, 744, 372, 128,  64,  64, 23};
    const float* SRC[12] = {W_dna, W_img, W_qkv, W_o, W_f1, W_f2, W_d1, W_d2, W_fp, W_ge, W_s1, W_s2};
    PrepackArgs pa;
    size_t woff[12];
    size_t off = 0;
    for (int i = 0; i < 12; ++i) {
        pa.src[i] = SRC[i]; pa.K[i] = KK[i]; pa.N[i] = NN[i];
        pa.Kpad[i] = (KK[i] + 63) & ~63;
        pa.Nr[i]   = (NN[i] + 255) & ~255;
        pa.off[i] = off; woff[i] = off;
        off += (size_t)pa.Kpad[i] * pa.Nr[i];
    }
    const size_t AOFF = off;  // ~1.54M elems of weights (~3 MB)

    // activation layout (bf16 elems past AOFF; peak = AOFF + B*2048 ~ 137 MB):
    bf16* seq  = ws + AOFF;                         // [2B,256] row 2b+p = [dna|img]
    bf16* qkvf = ws + AOFF + (size_t)B * 512;       // [2B,768] = [B,2,768]
    bf16* ctxm = ws + AOFF;                         // [B,256]   (seq dead after qkv)
    bf16* fbuf = ws + AOFF + (size_t)B * 256;       // [B,256]
    bf16* h1   = ws + AOFF + (size_t)B * 512;       // [B,768]   (qkvf dead)
    bf16* g    = ws + AOFF + (size_t)B * 1280;      // [B,372]
    bf16* gbf  = ws + AOFF + (size_t)B * 512;       // [B,384]   (h1 dead)
    bf16* gf   = ws + AOFF + (size_t)B * 896;       // [B,192]
    bf16* sh   = ws + AOFF + (size_t)B * 1088;      // [B,64]

    float* out       = (float*)d_out;
    float* o_species = out;                          // [B,1050]
    float* o_local   = out + (size_t)B * 1050;       // [B,23]
    float* o_genus   = out + (size_t)B * 1073;       // [B,372]
    float* o_fused   = out + (size_t)B * 1445;       // [B,256]
    float* o_red     = out + (size_t)B * 1701;       // [B,128]

    prepack_kernel<<<dim3(64, 12), 256, 0, stream>>>(pa, ws);

#define NOF (float*)nullptr, 0
#define NOB (bf16*)nullptr, 0

    // dna_proj / img_proj -> seq [2B,256] (row 2b+p)
    gemm_mfma<float, 256, 0><<<dim3(1, 256), 512, 0, stream>>>(
        dna, 768, ws + woff[0], 768, b_dna, NOF, seq, 512, B, 256, 256, 768);
    gemm_mfma<float, 256, 0><<<dim3(1, 256), 512, 0, stream>>>(
        img, 512, ws + woff[1], 512, b_img, NOF, seq + 256, 512, B, 256, 256, 512);
    // qkv over all 2B rows, then attention
    gemm_mfma<bf16, 256, 0><<<dim3(3, 512), 512, 0, stream>>>(
        seq, 256, ws + woff[2], 256, b_qkv, NOF, qkvf, 768, 2 * B, 768, 768, 256);
    attn_kernel<<<B, 256, 0, stream>>>(qkvf, ctxm);
    // fused = mlp3(ctxm) -> output #4 (fp32) + bf16 copy
    mlp3_kernel<<<256, 512, 0, stream>>>(
        ctxm, ws + woff[3], b_o, ws + woff[4], b_f1, ws + woff[5], b_f2,
        o_fused, fbuf);
    // h1 = sigmoid(fused @ W_d1 + b_d1) [B,744] padded to 768 (zeros)
    gemm_mfma<bf16, 256, 2><<<dim3(3, 256), 512, 0, stream>>>(
        fbuf, 256, ws + woff[6], 256, b_d1, NOF, h1, 768, B, 744, 768, 256);
    // genus logits [B,372]
    gemm_mfma<bf16, 256, 0><<<dim3(2, 256), 512, 0, stream>>>(
        h1, 768, ws + woff[7], 768, b_d2, NOF, g, 372, B, 372, 372, 768);
    // genus softmax -> output #3 (fp32) + padded bf16 [B,384]
    softmax372_kernel<<<B, 64, 0, stream>>>(g, o_genus, gbf);
    // genus_emb -> gf[:,0:64]
    gemm_mfma<bf16, 128, 0><<<dim3(1, 256), 256, 0, stream>>>(
        gbf, 384, ws + woff[9], 384, b_ge, NOF, gf, 192, B, 64, 64, 384);
    // reduced_fused -> output #5 (fp32) and gf[:,64:192]
    gemm_mfma<bf16, 128, 0><<<dim3(1, 256), 256, 0, stream>>>(
        fbuf, 256, ws + woff[8], 256, b_fp, o_red, 128, gf + 64, 192, B, 128, 128, 256);
    // sh = sigmoid(gf @ W_s1 + b_s1) [B,64]
    gemm_mfma<bf16, 128, 2><<<dim3(1, 256), 256, 0, stream>>>(
        gf, 192, ws + woff[10], 192, b_s1, NOF, sh, 64, B, 64, 64, 192);
    // local_logits [B,23] -> output #2 (fp32)
    gemm_mfma<bf16, 128, 0><<<dim3(1, 256), 256, 0, stream>>>(
        sh, 64, ws + woff[11], 64, b_s2, o_local, 23, NOB, B, 23, 23, 64);
    // species -> output #1 (fp32)
    species_kernel<<<dim3(5, B), 256, 0, stream>>>(o_genus, o_local, sg, sl, o_species);
#undef NOF
#undef NOB
}